// Round 10
// baseline (280.463 us; speedup 1.0000x reference)
//
#include <hip/hip_runtime.h>
#include <hip/hip_bf16.h>
#include <type_traits>

#define N_NODES 10000
#define N_PAD   10112          // 79 * 128
#define N_EDGES 160000
#define D_H 512
#define BN_EPS 1e-5f
#define LEAKY_SLOPE 0.2f

typedef __attribute__((ext_vector_type(8))) __bf16 bf16x8;
typedef __attribute__((ext_vector_type(4))) __bf16 bf16x4;
typedef __attribute__((ext_vector_type(4))) float f32x4;

// ---- init: zero stats(5x16x1024)+cvec(5x512)=84480 f; counts; deg; dummy rows ----

__global__ void k_zeroinit(float* fz, int* counts, float* deg,
                           __hip_bfloat16* hb, __hip_bfloat16* ybuf) {
    int i = blockIdx.x * 256 + threadIdx.x;
    if (i < 84480) fz[i] = 0.f;
    if (i < N_NODES) { counts[i] = 0; deg[i] = 1.0f; }   // 1.0 = self-loop
    else if (i == N_NODES) deg[i] = 0.f;                 // dummy node -> dinv 0
    if (i < 128) ((unsigned int*)(hb + (size_t)N_NODES * 256))[i] = 0u;   // zero row (256 bf16)
    if (i < 256) ((unsigned int*)(ybuf + (size_t)N_NODES * D_H))[i] = 0u; // zero row (512 bf16)
}

__global__ void k_count(const int* __restrict__ ei, float* deg, int* counts) {
    int e = blockIdx.x * blockDim.x + threadIdx.x;
    if (e < N_EDGES) {
        int dst = ei[N_EDGES + e];
        atomicAdd(&deg[dst], 1.0f);
        atomicAdd(&counts[dst], 1);
    }
}

// exclusive scan of counts padded to multiple of 8 -> rowptr/cursor; deg -> dinv in place
__global__ __launch_bounds__(1024) void k_scan(const int* __restrict__ counts,
                                               int* rowptr, int* cursor, float* deg) {
    __shared__ int sums[1024];
    int t = threadIdx.x;
    int vals[10];
    int base = t * 10;
    int s = 0;
    #pragma unroll
    for (int j = 0; j < 10; j++) {
        int idx = base + j;
        int v = 0;
        if (idx < N_NODES) {
            v = (counts[idx] + 7) & ~7;                  // pad to multiple of 8
            deg[idx] = rsqrtf(deg[idx]);
        }
        vals[j] = v; s += v;
    }
    sums[t] = s;
    __syncthreads();
    for (int off = 1; off < 1024; off <<= 1) {
        int v = (t >= off) ? sums[t - off] : 0;
        __syncthreads();
        if (t >= off) sums[t] += v;
        __syncthreads();
    }
    int excl = (t == 0) ? 0 : sums[t - 1];
    #pragma unroll
    for (int j = 0; j < 10; j++) {
        int idx = base + j;
        if (idx < N_NODES) { rowptr[idx] = excl; cursor[idx] = excl; excl += vals[j]; }
    }
    if (t == 1023) rowptr[N_NODES] = sums[1023];
}

__global__ void k_fill(const int* __restrict__ ei, int* cursor, int* colidx) {
    int e = blockIdx.x * blockDim.x + threadIdx.x;
    if (e < N_EDGES) {
        int src = ei[e];
        int dst = ei[N_EDGES + e];
        int p = atomicAdd(&cursor[dst], 1);
        colidx[p] = src;
    }
}

// ---- merged prep: b<1250 convert x*dinv; b<1378 transpose W0; else pad colidx + aggw ----

__global__ __launch_bounds__(256) void k_prep0(const float* __restrict__ x,
        __hip_bfloat16* __restrict__ hb, const float* __restrict__ w,
        __hip_bfloat16* __restrict__ wt, const int* __restrict__ rowptr,
        const int* __restrict__ cursor, int* colidx,
        const float* __restrict__ dinv, float* __restrict__ aggw) {
    int b = blockIdx.x;
    if (b < 1250) {
        int i = b * 256 + threadIdx.x;
        float di = dinv[i >> 5];                 // row = i*8/256
        size_t base = (size_t)i * 8;
        float4 a = *reinterpret_cast<const float4*>(x + base);
        float4 c = *reinterpret_cast<const float4*>(x + base + 4);
        bf16x8 o;
        o[0] = (__bf16)(a.x * di); o[1] = (__bf16)(a.y * di);
        o[2] = (__bf16)(a.z * di); o[3] = (__bf16)(a.w * di);
        o[4] = (__bf16)(c.x * di); o[5] = (__bf16)(c.y * di);
        o[6] = (__bf16)(c.z * di); o[7] = (__bf16)(c.w * di);
        *reinterpret_cast<bf16x8*>((unsigned short*)hb + base) = o;
    } else if (b < 1378) {
        int bb = b - 1250;                 // 128 blocks: 8 x 16 tiles of 32x32
        int r0 = (bb & 7) * 32;            // k dim (256)
        int c0 = (bb >> 3) * 32;           // out-col dim (512)
        __shared__ float t[32][33];
        int tx = threadIdx.x & 31, ty = threadIdx.x >> 5;
        for (int rr = ty; rr < 32; rr += 8)
            t[rr][tx] = w[(size_t)(r0 + rr) * 512 + c0 + tx];
        __syncthreads();
        for (int rr = ty; rr < 32; rr += 8)
            wt[(size_t)(c0 + rr) * 256 + r0 + tx] = __float2bfloat16(t[tx][rr]);
    } else {
        int i = (b - 1378) * 256 + threadIdx.x;
        if (i < N_NODES) {
            int beg = rowptr[i], real_end = cursor[i], end = rowptr[i + 1];
            for (int e = real_end; e < end; e++) colidx[e] = N_NODES;
            float di = dinv[i], s = di;
            for (int e = beg; e < real_end; e++) s += dinv[colidx[e]];
            aggw[i] = di * s;
        }
    }
}

// ---- BN fold body: Wts[col][k] = bf16(sc[k]*W[k][col]); cvec[col] += sh[k]*W[k][col] ----
// stats layout: 16 buckets x [sum(512) | sumsq(512)]

__device__ void fold_body(int r0, int c0, const float* __restrict__ W,
        const float* __restrict__ g, const float* __restrict__ beta,
        const float* __restrict__ stats, __hip_bfloat16* __restrict__ Wts,
        float* __restrict__ cvec) {
    __shared__ float t[32][33];
    __shared__ float scs[32], shs[32];
    __shared__ float cpart[8][32];
    int tx = threadIdx.x & 31, ty = threadIdx.x >> 5;
    if (threadIdx.x < 32) {
        int k = r0 + threadIdx.x;
        float ssum = 0.f, qsum = 0.f;
        #pragma unroll
        for (int b = 0; b < 16; b++) {
            ssum += stats[b * 1024 + k];
            qsum += stats[b * 1024 + 512 + k];
        }
        float mu = ssum * (1.f / N_NODES);
        float var = qsum * (1.f / N_NODES) - mu * mu;
        float sc = rsqrtf(var + BN_EPS) * g[k];
        scs[threadIdx.x] = sc;
        shs[threadIdx.x] = beta[k] - mu * sc;
    }
    for (int rr = ty; rr < 32; rr += 8)
        t[rr][tx] = W[(size_t)(r0 + rr) * 512 + c0 + tx];
    __syncthreads();
    for (int rr = ty; rr < 32; rr += 8)
        Wts[(size_t)(c0 + rr) * 512 + r0 + tx] = __float2bfloat16(t[tx][rr] * scs[tx]);
    float p = 0.f;
    #pragma unroll
    for (int k = 0; k < 4; ++k) p += shs[ty * 4 + k] * t[ty * 4 + k][tx];
    cpart[ty][tx] = p;
    __syncthreads();
    if (ty == 0) {
        float s = 0.f;
        #pragma unroll
        for (int k2 = 0; k2 < 8; ++k2) s += cpart[k2][tx];
        atomicAdd(&cvec[c0 + tx], s);
    }
}

__global__ __launch_bounds__(256) void k_fold(const float* __restrict__ W,
        const float* __restrict__ g, const float* __restrict__ beta,
        const float* __restrict__ stats, __hip_bfloat16* __restrict__ Wts,
        float* __restrict__ cvec) {
    fold_body(blockIdx.x * 32, blockIdx.y * 32, W, g, beta, stats, Wts, cvec);
}

// ---- pure gather-sum aggregation (+ optional fused fold blocks at front) ----
// src rows PRE-SCALED by dinv[src]; CSR padded to 8, pads hit the zero row.
// dst[i] = dinv[i] * (src[i] + sum_e src[colidx[e]])

template<int COLS, int FOLD>
__global__ __launch_bounds__(256) void k_agg(const __hip_bfloat16* __restrict__ src,
        const int* __restrict__ rowptr, const int* __restrict__ colidx,
        const float* __restrict__ dinv, __hip_bfloat16* __restrict__ dst,
        const float* __restrict__ W, const float* __restrict__ g,
        const float* __restrict__ beta, const float* __restrict__ stats,
        __hip_bfloat16* __restrict__ Wts, float* __restrict__ cvec) {
    int b = blockIdx.x;
    if (FOLD) {
        if (b < 256) {                     // 256 blocks: 16 x 16 tiles of 32x32
            fold_body((b & 15) * 32, (b >> 4) * 32, W, g, beta, stats, Wts, cvec);
            return;
        }
        b -= 256;
    }
    constexpr int VL = COLS / 64;
    using vec_t = typename std::conditional<VL == 8, bf16x8, bf16x4>::type;
    int w = threadIdx.x >> 6, lane = threadIdx.x & 63;
    int gw = b * 4 + w;                    // 0..8191
    int col0 = lane * VL;
    const __hip_bfloat16* base = src + col0;
    for (int node = gw; node < N_NODES; node += 8192) {
        float di = dinv[node];
        vec_t v = *reinterpret_cast<const vec_t*>(base + (size_t)node * COLS);
        float s[VL];
        #pragma unroll
        for (int j = 0; j < VL; j++) s[j] = (float)v[j];
        int beg = rowptr[node], end = rowptr[node + 1];
        if (beg < end) {
            int4 iv0 = *reinterpret_cast<const int4*>(colidx + beg);
            int4 iv1 = *reinterpret_cast<const int4*>(colidx + beg + 4);
            for (int e = beg; e < end; e += 8) {
                int4 nv0 = iv0, nv1 = iv1;
                int en = e + 8;
                if (en < end) {            // prefetch next indices before consuming rows
                    nv0 = *reinterpret_cast<const int4*>(colidx + en);
                    nv1 = *reinterpret_cast<const int4*>(colidx + en + 4);
                }
                vec_t u0 = *reinterpret_cast<const vec_t*>(base + (size_t)iv0.x * COLS);
                vec_t u1 = *reinterpret_cast<const vec_t*>(base + (size_t)iv0.y * COLS);
                vec_t u2 = *reinterpret_cast<const vec_t*>(base + (size_t)iv0.z * COLS);
                vec_t u3 = *reinterpret_cast<const vec_t*>(base + (size_t)iv0.w * COLS);
                vec_t u4 = *reinterpret_cast<const vec_t*>(base + (size_t)iv1.x * COLS);
                vec_t u5 = *reinterpret_cast<const vec_t*>(base + (size_t)iv1.y * COLS);
                vec_t u6 = *reinterpret_cast<const vec_t*>(base + (size_t)iv1.z * COLS);
                vec_t u7 = *reinterpret_cast<const vec_t*>(base + (size_t)iv1.w * COLS);
                #pragma unroll
                for (int j = 0; j < VL; j++)
                    s[j] += (((float)u0[j] + (float)u1[j]) + ((float)u2[j] + (float)u3[j]))
                          + (((float)u4[j] + (float)u5[j]) + ((float)u6[j] + (float)u7[j]));
                iv0 = nv0; iv1 = nv1;
            }
        }
        vec_t o;
        #pragma unroll
        for (int j = 0; j < VL; j++) o[j] = (__bf16)(di * s[j]);
        *reinterpret_cast<vec_t*>(dst + (size_t)node * COLS + col0) = o;
    }
}

// ---- bf16 MFMA GEMM: 128x128 tile, 4 waves (2x2, 64x64/wave), 2-phase dbuf,
//      counted vmcnt(4) pipeline, bijective XCD swizzle for 316 blocks ----
// MODE 0: val=acc+bias1(+aggw*cvec); leaky; stats; write bf16(val*dinv[row])   (layers 0-3)
// MODE 1: val=acc+bias1+aggw*cvec; stats; write bf16(val)                      (layer 4)
// MODE 2: write f32 acc+bias1+bias2                                            (final)

__device__ __forceinline__ void gload16(const void* g, void* l) {
    __builtin_amdgcn_global_load_lds(
        (const __attribute__((address_space(1))) void*)g,
        (__attribute__((address_space(3))) void*)l, 16, 0, 0);
}

template<int MODE, int HASR1, int K>
__global__ __launch_bounds__(256) void k_gemm(
        const __hip_bfloat16* __restrict__ A,    // [N_PAD x K] row-major
        const __hip_bfloat16* __restrict__ Bt,   // [512 x K] row-major
        const float* __restrict__ dinv, const float* __restrict__ aggw,
        const float* __restrict__ bias1, const float* __restrict__ bias2,
        const float* __restrict__ cvec,
        __hip_bfloat16* __restrict__ Cb, float* __restrict__ Cf,
        float* __restrict__ stats) {
    __shared__ alignas(16) __hip_bfloat16 As[2][128][32];
    __shared__ alignas(16) __hip_bfloat16 Bs[2][128][32];
    // bijective XCD swizzle: nwg=316, q=39, r=4 (m204 formula)
    int lin = blockIdx.x;
    int xcd = lin & 7, idx = lin >> 3;
    int wgid = (xcd < 4) ? xcd * 40 + idx : 160 + (xcd - 4) * 39 + idx;
    int row0 = (wgid >> 2) * 128;
    int col0 = (wgid & 3) * 128;
    int tid = threadIdx.x;
    int lane = tid & 63;
    int w = tid >> 6;
    int wm = w >> 1, wn = w & 1;
    int sr = lane >> 2;
    int sk = (((lane & 3) ^ ((lane >> 3) & 3)) << 3);     // pre-swizzled global k offset
    int fl = lane & 15;
    int fso = (((lane >> 4) ^ ((lane >> 1) & 3)) << 3);   // swizzled frag slot offset

    const __hip_bfloat16* ga = A  + (size_t)(row0 + w * 16 + sr) * K + sk;
    const __hip_bfloat16* gb = Bt + (size_t)(col0 + w * 16 + sr) * K + sk;

    f32x4 acc[4][4] = {};
    constexpr int NSTEP = K / 32;

    // prologue: stage tile 0 (4 outstanding vmem ops per wave)
    gload16(ga, &As[0][w * 16][0]);
    gload16(ga + (size_t)64 * K, &As[0][(w + 4) * 16][0]);
    gload16(gb, &Bs[0][w * 16][0]);
    gload16(gb + (size_t)64 * K, &Bs[0][(w + 4) * 16][0]);

    #pragma unroll
    for (int t = 0; t < NSTEP; ++t) {
        int cur = t & 1;
        if (t + 1 < NSTEP) {
            // stage next tile; wait only CURRENT tile's 4 loads (next's 4 stay in flight)
            int k0 = (t + 1) * 32;
            gload16(ga + k0, &As[cur ^ 1][w * 16][0]);
            gload16(ga + (size_t)64 * K + k0, &As[cur ^ 1][(w + 4) * 16][0]);
            gload16(gb + k0, &Bs[cur ^ 1][w * 16][0]);
            gload16(gb + (size_t)64 * K + k0, &Bs[cur ^ 1][(w + 4) * 16][0]);
            asm volatile("s_waitcnt vmcnt(4)\n\ts_barrier" ::: "memory");
        } else {
            asm volatile("s_waitcnt vmcnt(0)\n\ts_barrier" ::: "memory");
        }
        bf16x8 af[4], bfr[4];
        #pragma unroll
        for (int i = 0; i < 4; ++i)
            af[i]  = *reinterpret_cast<const bf16x8*>(&As[cur][wm * 64 + i * 16 + fl][fso]);
        #pragma unroll
        for (int j = 0; j < 4; ++j)
            bfr[j] = *reinterpret_cast<const bf16x8*>(&Bs[cur][wn * 64 + j * 16 + fl][fso]);
        #pragma unroll
        for (int i = 0; i < 4; ++i)
            #pragma unroll
            for (int j = 0; j < 4; ++j)
                acc[i][j] = __builtin_amdgcn_mfma_f32_16x16x32_bf16(af[i], bfr[j], acc[i][j], 0, 0, 0);
        // all this wave's ds_reads complete before barrier -> next iter's stage
        // can't overwrite a buffer another wave is still reading
        asm volatile("s_waitcnt lgkmcnt(0)\n\ts_barrier" ::: "memory");
    }

    int rg = (lane >> 4) * 4;             // C/D: col=lane&15, row=(lane>>4)*4+reg
    float sp[4] = {}, qp[4] = {};
    #pragma unroll
    for (int i = 0; i < 4; ++i) {
        #pragma unroll
        for (int r = 0; r < 4; ++r) {
            int row = row0 + wm * 64 + i * 16 + rg + r;
            if (row < N_NODES) {
                float r1 = HASR1 ? aggw[row] : 0.f;
                float dsc = (MODE == 0) ? dinv[row] : 1.f;
                #pragma unroll
                for (int j = 0; j < 4; ++j) {
                    int col = col0 + wn * 64 + j * 16 + fl;
                    float val = acc[i][j][r] + bias1[col];
                    if (HASR1) val += r1 * cvec[col];
                    if (MODE == 0) val = (val >= 0.f) ? val : LEAKY_SLOPE * val;
                    if (MODE <= 1) { sp[j] += val; qp[j] += val * val; }
                    if (MODE == 2) Cf[(size_t)row * D_H + col] = val + bias2[col];
                    else           Cb[(size_t)row * D_H + col] = __float2bfloat16(val * dsc);
                }
            }
        }
    }
    if (MODE <= 1) {                      // fused BN-stats reduce (reuse LDS, 8KB)
        float* red = reinterpret_cast<float*>(&As[0][0][0]);   // [2][128][8]
        int contrib = wm * 4 + (lane >> 4);
        #pragma unroll
        for (int j = 0; j < 4; ++j) {
            int cl = wn * 64 + j * 16 + fl;                    // 0..127
            red[cl * 8 + contrib]        = sp[j];
            red[1024 + cl * 8 + contrib] = qp[j];
        }
        __syncthreads();
        {
            int c = tid >> 1, isq = tid & 1;                   // 128 cols x 2
            float ssum = 0.f;
            #pragma unroll
            for (int k = 0; k < 8; k++) ssum += red[isq * 1024 + c * 8 + k];
            atomicAdd(&stats[(wgid & 15) * 1024 + isq * 512 + col0 + c], ssum);
        }
    }
}

// ---------------- launch ----------------

extern "C" void kernel_launch(void* const* d_in, const int* in_sizes, int n_in,
                              void* d_out, int out_size, void* d_ws, size_t ws_size,
                              hipStream_t stream) {
    (void)in_sizes; (void)n_in; (void)out_size; (void)ws_size;
    const float* x  = (const float*)d_in[0];
    const int*   ei = (const int*)d_in[1];
    const float *W[6], *bb[5], *gg[5], *beb[5];
    for (int i = 0; i < 5; i++) {
        W[i]   = (const float*)d_in[2 + 4 * i];
        bb[i]  = (const float*)d_in[3 + 4 * i];
        gg[i]  = (const float*)d_in[4 + 4 * i];
        beb[i] = (const float*)d_in[5 + 4 * i];
    }
    W[5] = (const float*)d_in[22];
    const float* bf = (const float*)d_in[23];
    float* out = (float*)d_out;

    // workspace layout (all chunks 16B-aligned)
    char* p = (char*)d_ws;
    __hip_bfloat16* hb   = (__hip_bfloat16*)p;  p += (size_t)N_PAD * 256 * 2;   // x*dinv
    __hip_bfloat16* G    = (__hip_bfloat16*)p;  p += (size_t)N_PAD * D_H * 2;   // agg output
    __hip_bfloat16* ybuf = (__hip_bfloat16*)p;  p += (size_t)N_PAD * D_H * 2;   // gemm output
    __hip_bfloat16* Wt0  = (__hip_bfloat16*)p;  p += (size_t)D_H * 256 * 2;
    __hip_bfloat16* Wts  = (__hip_bfloat16*)p;  p += (size_t)D_H * 512 * 2;
    float* stats  = (float*)p;  p += 5 * 16384 * 4;  // [5][16 buckets][1024]
    float* cbuf   = (float*)p;  p += 5 * 512 * 4;    // contiguous with stats for zeroing
    float* dinv   = (float*)p;  p += 10008 * 4;
    float* aggw   = (float*)p;  p += N_NODES * 4;
    int* counts   = (int*)p;    p += N_NODES * 4;
    int* rowptr   = (int*)p;    p += 10004 * 4;
    int* cursor   = (int*)p;    p += N_NODES * 4;
    int* colidx   = (int*)p;                         // <= 230000 ints (pad-8)

    // preprocessing
    k_zeroinit<<<330, 256, 0, stream>>>(stats, counts, dinv, hb, ybuf);
    k_count<<<(N_EDGES + 255) / 256, 256, 0, stream>>>(ei, dinv, counts);
    k_scan<<<1, 1024, 0, stream>>>(counts, rowptr, cursor, dinv);
    k_fill<<<(N_EDGES + 255) / 256, 256, 0, stream>>>(ei, cursor, colidx);
    k_prep0<<<1418, 256, 0, stream>>>(x, hb, W[0], Wt0, rowptr, cursor, colidx, dinv, aggw);

    const int GGRID = 316;        // (10112/128) * (512/128)

    // layer 0: agg(x') -> G[256]; GEMM0 -> ybuf (leaky+stats0+prescale)
    k_agg<256, 0><<<2048, 256, 0, stream>>>(hb, rowptr, colidx, dinv, G,
            nullptr, nullptr, nullptr, nullptr, nullptr, nullptr);
    k_gemm<0, 0, 256><<<GGRID, 256, 0, stream>>>(G, Wt0, dinv, nullptr, bb[0], nullptr,
            nullptr, ybuf, nullptr, stats);

    // layers 1..3: [fold_l + agg] -> GEMM_l (leaky+stats_l+prescale)
    for (int l = 1; l < 4; l++) {
        k_agg<512, 1><<<2304, 256, 0, stream>>>(ybuf, rowptr, colidx, dinv, G,
                W[l], gg[l - 1], beb[l - 1], stats + (l - 1) * 16384, Wts,
                cbuf + (l - 1) * 512);
        k_gemm<0, 1, 512><<<GGRID, 256, 0, stream>>>(G, Wts, dinv, aggw, bb[l], nullptr,
                cbuf + (l - 1) * 512, ybuf, nullptr, stats + l * 16384);
    }
    // layer 4: [fold4 + agg] -> GEMM4 (stats4, plain bf16 write)
    k_agg<512, 1><<<2304, 256, 0, stream>>>(ybuf, rowptr, colidx, dinv, G,
            W[4], gg[3], beb[3], stats + 3 * 16384, Wts, cbuf + 3 * 512);
    k_gemm<1, 1, 512><<<GGRID, 256, 0, stream>>>(G, Wts, nullptr, aggw, bb[4], nullptr,
            cbuf + 3 * 512, ybuf, nullptr, stats + 4 * 16384);

    // final: fold5(Wf, stats4); GEMM5 -> out f32 (bias = cvec4 + bf)
    k_fold<<<dim3(16, 16), 256, 0, stream>>>(W[5], gg[4], beb[4],
            stats + 4 * 16384, Wts, cbuf + 4 * 512);
    k_gemm<2, 0, 512><<<GGRID, 256, 0, stream>>>(ybuf, Wts, nullptr, nullptr,
            cbuf + 4 * 512, bf, nullptr, nullptr, out, nullptr);
}

// Round 11
// 253.494 us; speedup vs baseline: 1.1064x; 1.1064x over previous
//
#include <hip/hip_runtime.h>
#include <hip/hip_bf16.h>
#include <type_traits>

#define N_NODES 10000
#define N_PAD   10112          // 79 * 128
#define N_EDGES 160000
#define D_H 512
#define BN_EPS 1e-5f
#define LEAKY_SLOPE 0.2f

typedef __attribute__((ext_vector_type(8))) __bf16 bf16x8;
typedef __attribute__((ext_vector_type(4))) __bf16 bf16x4;
typedef __attribute__((ext_vector_type(4))) float f32x4;

// ---- init: zero stats(5x16x1024)+cvec(5x512)=84480 f; counts; dummy rows ----

__global__ void k_zeroinit(float* fz, int* counts,
                           __hip_bfloat16* hb, __hip_bfloat16* ybuf) {
    int i = blockIdx.x * 256 + threadIdx.x;
    if (i < 84480) fz[i] = 0.f;
    if (i < N_NODES) counts[i] = 0;
    if (i < 128) ((unsigned int*)(hb + (size_t)N_NODES * 256))[i] = 0u;   // zero row (256 bf16)
    if (i < 256) ((unsigned int*)(ybuf + (size_t)N_NODES * D_H))[i] = 0u; // zero row (512 bf16)
}

__global__ void k_count(const int* __restrict__ ei, int* counts) {
    int e = blockIdx.x * blockDim.x + threadIdx.x;
    if (e < N_EDGES) atomicAdd(&counts[ei[N_EDGES + e]], 1);
}

// exclusive scan of counts padded to multiple of 8 -> rowptr/cursor;
// dinv[i] = rsqrtf(1 + count) (self-loop); dinv[dummy] = 0
__global__ __launch_bounds__(1024) void k_scan(const int* __restrict__ counts,
                                               int* rowptr, int* cursor, float* dinv) {
    __shared__ int sums[1024];
    int t = threadIdx.x;
    int vals[10];
    int base = t * 10;
    int s = 0;
    #pragma unroll
    for (int j = 0; j < 10; j++) {
        int idx = base + j;
        int v = 0;
        if (idx < N_NODES) {
            int c = counts[idx];
            v = (c + 7) & ~7;                            // pad to multiple of 8
            dinv[idx] = rsqrtf(1.0f + (float)c);         // deg = count + self-loop
        } else if (idx == N_NODES) {
            dinv[idx] = 0.f;                             // dummy node
        }
        vals[j] = v; s += v;
    }
    sums[t] = s;
    __syncthreads();
    for (int off = 1; off < 1024; off <<= 1) {
        int v = (t >= off) ? sums[t - off] : 0;
        __syncthreads();
        if (t >= off) sums[t] += v;
        __syncthreads();
    }
    int excl = (t == 0) ? 0 : sums[t - 1];
    #pragma unroll
    for (int j = 0; j < 10; j++) {
        int idx = base + j;
        if (idx < N_NODES) { rowptr[idx] = excl; cursor[idx] = excl; excl += vals[j]; }
    }
    if (t == 1023) rowptr[N_NODES] = sums[1023];
}

// ---- merged prep: xcvt (1250) | wt0 transpose (128) | fill (625) | pad (40) ----
// fill writes real CSR slots; pad writes [rowptr+count, rowptr_next) -- disjoint.

__global__ __launch_bounds__(256) void k_prep(const float* __restrict__ x,
        __hip_bfloat16* __restrict__ hb, const float* __restrict__ w,
        __hip_bfloat16* __restrict__ wt, const int* __restrict__ ei,
        const int* __restrict__ rowptr, const int* __restrict__ counts,
        int* cursor, int* colidx, const float* __restrict__ dinv) {
    int b = blockIdx.x;
    if (b < 1250) {
        int i = b * 256 + threadIdx.x;
        float di = dinv[i >> 5];                 // row = i*8/256
        size_t base = (size_t)i * 8;
        float4 a = *reinterpret_cast<const float4*>(x + base);
        float4 c = *reinterpret_cast<const float4*>(x + base + 4);
        bf16x8 o;
        o[0] = (__bf16)(a.x * di); o[1] = (__bf16)(a.y * di);
        o[2] = (__bf16)(a.z * di); o[3] = (__bf16)(a.w * di);
        o[4] = (__bf16)(c.x * di); o[5] = (__bf16)(c.y * di);
        o[6] = (__bf16)(c.z * di); o[7] = (__bf16)(c.w * di);
        *reinterpret_cast<bf16x8*>((unsigned short*)hb + base) = o;
    } else if (b < 1378) {
        int bb = b - 1250;                 // 128 blocks: 8 x 16 tiles of 32x32
        int r0 = (bb & 7) * 32;            // k dim (256)
        int c0 = (bb >> 3) * 32;           // out-col dim (512)
        __shared__ float t[32][33];
        int tx = threadIdx.x & 31, ty = threadIdx.x >> 5;
        for (int rr = ty; rr < 32; rr += 8)
            t[rr][tx] = w[(size_t)(r0 + rr) * 512 + c0 + tx];
        __syncthreads();
        for (int rr = ty; rr < 32; rr += 8)
            wt[(size_t)(c0 + rr) * 256 + r0 + tx] = __float2bfloat16(t[tx][rr]);
    } else if (b < 2003) {
        int e = (b - 1378) * 256 + threadIdx.x;
        if (e < N_EDGES) {
            int src = ei[e];
            int dst = ei[N_EDGES + e];
            int p = atomicAdd(&cursor[dst], 1);
            colidx[p] = src;
        }
    } else {
        int i = (b - 2003) * 256 + threadIdx.x;
        if (i < N_NODES) {
            int beg = rowptr[i] + counts[i], end = rowptr[i + 1];
            for (int e = beg; e < end; e++) colidx[e] = N_NODES;
        }
    }
}

// ---- BN fold body: Wts[col][k] = bf16(sc[k]*W[k][col]); cvec[col] += sh[k]*W[k][col] ----
// stats layout: 16 buckets x [sum(512) | sumsq(512)]

__device__ void fold_body(int r0, int c0, const float* __restrict__ W,
        const float* __restrict__ g, const float* __restrict__ beta,
        const float* __restrict__ stats, __hip_bfloat16* __restrict__ Wts,
        float* __restrict__ cvec) {
    __shared__ float t[32][33];
    __shared__ float scs[32], shs[32];
    __shared__ float cpart[8][32];
    int tx = threadIdx.x & 31, ty = threadIdx.x >> 5;
    if (threadIdx.x < 32) {
        int k = r0 + threadIdx.x;
        float ssum = 0.f, qsum = 0.f;
        #pragma unroll
        for (int b = 0; b < 16; b++) {
            ssum += stats[b * 1024 + k];
            qsum += stats[b * 1024 + 512 + k];
        }
        float mu = ssum * (1.f / N_NODES);
        float var = qsum * (1.f / N_NODES) - mu * mu;
        float sc = rsqrtf(var + BN_EPS) * g[k];
        scs[threadIdx.x] = sc;
        shs[threadIdx.x] = beta[k] - mu * sc;
    }
    for (int rr = ty; rr < 32; rr += 8)
        t[rr][tx] = W[(size_t)(r0 + rr) * 512 + c0 + tx];
    __syncthreads();
    for (int rr = ty; rr < 32; rr += 8)
        Wts[(size_t)(c0 + rr) * 512 + r0 + tx] = __float2bfloat16(t[tx][rr] * scs[tx]);
    float p = 0.f;
    #pragma unroll
    for (int k = 0; k < 4; ++k) p += shs[ty * 4 + k] * t[ty * 4 + k][tx];
    cpart[ty][tx] = p;
    __syncthreads();
    if (ty == 0) {
        float s = 0.f;
        #pragma unroll
        for (int k2 = 0; k2 < 8; ++k2) s += cpart[k2][tx];
        atomicAdd(&cvec[c0 + tx], s);
    }
}

__global__ __launch_bounds__(256) void k_fold(const float* __restrict__ W,
        const float* __restrict__ g, const float* __restrict__ beta,
        const float* __restrict__ stats, __hip_bfloat16* __restrict__ Wts,
        float* __restrict__ cvec) {
    fold_body(blockIdx.x * 32, blockIdx.y * 32, W, g, beta, stats, Wts, cvec);
}

// ---- pure gather-sum aggregation (+ fused tail blocks) ----
// src rows PRE-SCALED by dinv[src]; CSR padded to 8, pads hit the zero row.
// dst[i] = dinv[i] * (src[i] + sum_e src[colidx[e]])
// TAIL: 0 none; 1 fold_body (blocks 2500..2755); 2 aggw compute (blocks 2500..2539)

template<int COLS, int TAIL>
__global__ __launch_bounds__(256) void k_agg(const __hip_bfloat16* __restrict__ src,
        const int* __restrict__ rowptr, const int* __restrict__ colidx,
        const float* __restrict__ dinv, __hip_bfloat16* __restrict__ dst,
        float* __restrict__ aggw,
        const float* __restrict__ W, const float* __restrict__ g,
        const float* __restrict__ beta, const float* __restrict__ stats,
        __hip_bfloat16* __restrict__ Wts, float* __restrict__ cvec) {
    if (TAIL == 1 && blockIdx.x >= 2500) {
        int bb = blockIdx.x - 2500;        // 256 blocks: 16 x 16 tiles of 32x32
        fold_body((bb & 15) * 32, (bb >> 4) * 32, W, g, beta, stats, Wts, cvec);
        return;
    }
    if (TAIL == 2 && blockIdx.x >= 2500) {
        int i = (blockIdx.x - 2500) * 256 + threadIdx.x;
        if (i < N_NODES) {
            float di = dinv[i], s = di;
            int end = rowptr[i + 1];
            for (int e = rowptr[i]; e < end; e++) s += dinv[colidx[e]];  // pads add 0
            aggw[i] = di * s;
        }
        return;
    }
    constexpr int VL = COLS / 64;
    using vec_t = typename std::conditional<VL == 8, bf16x8, bf16x4>::type;
    int w = threadIdx.x >> 6, lane = threadIdx.x & 63;
    int node = blockIdx.x * 4 + w;         // 2500*4 = 10000 exact
    int col0 = lane * VL;
    const __hip_bfloat16* base = src + col0;
    float di = dinv[node];
    vec_t v = *reinterpret_cast<const vec_t*>(base + (size_t)node * COLS);
    float s[VL];
    #pragma unroll
    for (int j = 0; j < VL; j++) s[j] = (float)v[j];
    int beg = rowptr[node], end = rowptr[node + 1];
    if (beg < end) {
        int4 iv0 = *reinterpret_cast<const int4*>(colidx + beg);
        int4 iv1 = *reinterpret_cast<const int4*>(colidx + beg + 4);
        for (int e = beg; e < end; e += 8) {
            int4 nv0 = iv0, nv1 = iv1;
            int en = e + 8;
            if (en < end) {                // prefetch next indices before consuming rows
                nv0 = *reinterpret_cast<const int4*>(colidx + en);
                nv1 = *reinterpret_cast<const int4*>(colidx + en + 4);
            }
            vec_t u0 = *reinterpret_cast<const vec_t*>(base + (size_t)iv0.x * COLS);
            vec_t u1 = *reinterpret_cast<const vec_t*>(base + (size_t)iv0.y * COLS);
            vec_t u2 = *reinterpret_cast<const vec_t*>(base + (size_t)iv0.z * COLS);
            vec_t u3 = *reinterpret_cast<const vec_t*>(base + (size_t)iv0.w * COLS);
            vec_t u4 = *reinterpret_cast<const vec_t*>(base + (size_t)iv1.x * COLS);
            vec_t u5 = *reinterpret_cast<const vec_t*>(base + (size_t)iv1.y * COLS);
            vec_t u6 = *reinterpret_cast<const vec_t*>(base + (size_t)iv1.z * COLS);
            vec_t u7 = *reinterpret_cast<const vec_t*>(base + (size_t)iv1.w * COLS);
            #pragma unroll
            for (int j = 0; j < VL; j++)
                s[j] += (((float)u0[j] + (float)u1[j]) + ((float)u2[j] + (float)u3[j]))
                      + (((float)u4[j] + (float)u5[j]) + ((float)u6[j] + (float)u7[j]));
            iv0 = nv0; iv1 = nv1;
        }
    }
    vec_t o;
    #pragma unroll
    for (int j = 0; j < VL; j++) o[j] = (__bf16)(di * s[j]);
    *reinterpret_cast<vec_t*>(dst + (size_t)node * COLS + col0) = o;
}

// ---- bf16 MFMA GEMM (128x64 tile, 2-phase dbuf, COUNTED vmcnt pipeline) ----
// MODE 0: val=acc+bias1(+aggw*cvec); leaky; stats; write bf16(val*dinv[row])   (layers 0-3)
// MODE 1: val=acc+bias1+aggw*cvec; stats; write bf16(val)                      (layer 4)
// MODE 2: write f32 acc+bias1+bias2                                            (final)

__device__ __forceinline__ void gload16(const void* g, void* l) {
    __builtin_amdgcn_global_load_lds(
        (const __attribute__((address_space(1))) void*)g,
        (__attribute__((address_space(3))) void*)l, 16, 0, 0);
}

template<int MODE, int HASR1, int K>
__global__ __launch_bounds__(256) void k_gemm(
        const __hip_bfloat16* __restrict__ A,    // [N_PAD x K] row-major
        const __hip_bfloat16* __restrict__ Bt,   // [512 x K] row-major
        const float* __restrict__ dinv, const float* __restrict__ aggw,
        const float* __restrict__ bias1, const float* __restrict__ bias2,
        const float* __restrict__ cvec,
        __hip_bfloat16* __restrict__ Cb, float* __restrict__ Cf,
        float* __restrict__ stats) {
    __shared__ alignas(16) __hip_bfloat16 As[2][128][32];
    __shared__ alignas(16) __hip_bfloat16 Bs[2][64][32];
    int lin = blockIdx.y * 8 + blockIdx.x;
    int nid = (lin & 7) * 79 + (lin >> 3);       // bijective XCD swizzle (632 = 8*79)
    int row0 = (nid >> 3) * 128;
    int col0 = (nid & 7) * 64;
    int tid = threadIdx.x;
    int lane = tid & 63;
    int w = tid >> 6;
    int wm = w >> 1, wn = w & 1;
    int sr = lane >> 2;
    int sk = (((lane & 3) ^ ((lane >> 3) & 3)) << 3);     // pre-swizzled global k offset
    int fl = lane & 15;
    int fso = (((lane >> 4) ^ ((lane >> 1) & 3)) << 3);   // swizzled frag slot offset

    const __hip_bfloat16* ga = A  + (size_t)(row0 + w * 16 + sr) * K + sk;
    const __hip_bfloat16* gb = Bt + (size_t)(col0 + w * 16 + sr) * K + sk;

    f32x4 acc[4][2] = {};
    constexpr int NSTEP = K / 32;

    // prologue: stage tile 0 (3 outstanding vmem ops per wave)
    gload16(ga, &As[0][w * 16][0]);
    gload16(ga + (size_t)64 * K, &As[0][(w + 4) * 16][0]);
    gload16(gb, &Bs[0][w * 16][0]);

    #pragma unroll
    for (int t = 0; t < NSTEP; ++t) {
        int cur = t & 1;
        if (t + 1 < NSTEP) {
            // stage next tile; wait only CURRENT tile's 3 loads (next's 3 stay in flight)
            int k0 = (t + 1) * 32;
            gload16(ga + k0, &As[cur ^ 1][w * 16][0]);
            gload16(ga + (size_t)64 * K + k0, &As[cur ^ 1][(w + 4) * 16][0]);
            gload16(gb + k0, &Bs[cur ^ 1][w * 16][0]);
            asm volatile("s_waitcnt vmcnt(3)\n\ts_barrier" ::: "memory");
        } else {
            asm volatile("s_waitcnt vmcnt(0)\n\ts_barrier" ::: "memory");
        }
        bf16x8 af[4], bfr[2];
        #pragma unroll
        for (int i = 0; i < 4; ++i)
            af[i]  = *reinterpret_cast<const bf16x8*>(&As[cur][wm * 64 + i * 16 + fl][fso]);
        #pragma unroll
        for (int j = 0; j < 2; ++j)
            bfr[j] = *reinterpret_cast<const bf16x8*>(&Bs[cur][wn * 32 + j * 16 + fl][fso]);
        #pragma unroll
        for (int i = 0; i < 4; ++i)
            #pragma unroll
            for (int j = 0; j < 2; ++j)
                acc[i][j] = __builtin_amdgcn_mfma_f32_16x16x32_bf16(af[i], bfr[j], acc[i][j], 0, 0, 0);
        // all this wave's ds_reads complete before barrier -> next iter's stage
        // can't overwrite a buffer another wave is still reading
        asm volatile("s_waitcnt lgkmcnt(0)\n\ts_barrier" ::: "memory");
    }

    int rg = (lane >> 4) * 4;             // C/D: col=lane&15, row=(lane>>4)*4+reg
    float sp0 = 0.f, sp1 = 0.f, qp0 = 0.f, qp1 = 0.f;
    #pragma unroll
    for (int i = 0; i < 4; ++i) {
        #pragma unroll
        for (int r = 0; r < 4; ++r) {
            int row = row0 + wm * 64 + i * 16 + rg + r;
            if (row < N_NODES) {
                float r1 = HASR1 ? aggw[row] : 0.f;
                float dsc = (MODE == 0) ? dinv[row] : 1.f;
                #pragma unroll
                for (int j = 0; j < 2; ++j) {
                    int col = col0 + wn * 32 + j * 16 + fl;
                    float val = acc[i][j][r] + bias1[col];
                    if (HASR1) val += r1 * cvec[col];
                    if (MODE == 0) val = (val >= 0.f) ? val : LEAKY_SLOPE * val;
                    if (MODE <= 1) {
                        if (j == 0) { sp0 += val; qp0 += val * val; }
                        else        { sp1 += val; qp1 += val * val; }
                    }
                    if (MODE == 2) Cf[(size_t)row * D_H + col] = val + bias2[col];
                    else           Cb[(size_t)row * D_H + col] = __float2bfloat16(val * dsc);
                }
            }
        }
    }
    if (MODE <= 1) {                      // fused BN-stats reduce (reuse LDS)
        float* red = reinterpret_cast<float*>(&As[0][0][0]);   // [2][512]
        int cl = wn * 32 + fl;            // col_local for j=0; +16 for j=1
        int contrib = wm * 4 + (lane >> 4);
        red[cl * 8 + contrib]          = sp0;
        red[(cl + 16) * 8 + contrib]   = sp1;
        red[512 + cl * 8 + contrib]        = qp0;
        red[512 + (cl + 16) * 8 + contrib] = qp1;
        __syncthreads();
        if (tid < 128) {
            int c = tid >> 1, isq = tid & 1;
            float ssum = 0.f;
            #pragma unroll
            for (int k = 0; k < 8; k++) ssum += red[isq * 512 + c * 8 + k];
            atomicAdd(&stats[(nid & 15) * 1024 + isq * 512 + col0 + c], ssum);
        }
    }
}

// ---------------- launch ----------------

extern "C" void kernel_launch(void* const* d_in, const int* in_sizes, int n_in,
                              void* d_out, int out_size, void* d_ws, size_t ws_size,
                              hipStream_t stream) {
    (void)in_sizes; (void)n_in; (void)out_size; (void)ws_size;
    const float* x  = (const float*)d_in[0];
    const int*   ei = (const int*)d_in[1];
    const float *W[6], *bb[5], *gg[5], *beb[5];
    for (int i = 0; i < 5; i++) {
        W[i]   = (const float*)d_in[2 + 4 * i];
        bb[i]  = (const float*)d_in[3 + 4 * i];
        gg[i]  = (const float*)d_in[4 + 4 * i];
        beb[i] = (const float*)d_in[5 + 4 * i];
    }
    W[5] = (const float*)d_in[22];
    const float* bf = (const float*)d_in[23];
    float* out = (float*)d_out;

    // workspace layout (all chunks 16B-aligned)
    char* p = (char*)d_ws;
    __hip_bfloat16* hb   = (__hip_bfloat16*)p;  p += (size_t)N_PAD * 256 * 2;   // x*dinv
    __hip_bfloat16* G    = (__hip_bfloat16*)p;  p += (size_t)N_PAD * D_H * 2;   // agg output
    __hip_bfloat16* ybuf = (__hip_bfloat16*)p;  p += (size_t)N_PAD * D_H * 2;   // gemm output
    __hip_bfloat16* Wt0  = (__hip_bfloat16*)p;  p += (size_t)D_H * 256 * 2;
    __hip_bfloat16* Wts  = (__hip_bfloat16*)p;  p += (size_t)D_H * 512 * 2;
    float* stats  = (float*)p;  p += 5 * 16384 * 4;  // [5][16 buckets][1024]
    float* cbuf   = (float*)p;  p += 5 * 512 * 4;    // contiguous with stats for zeroing
    float* dinv   = (float*)p;  p += 10008 * 4;      // [10000]=dummy 0
    float* aggw   = (float*)p;  p += N_NODES * 4;
    int* counts   = (int*)p;    p += N_NODES * 4;
    int* rowptr   = (int*)p;    p += 10004 * 4;
    int* cursor   = (int*)p;    p += N_NODES * 4;
    int* colidx   = (int*)p;                         // <= 230000 ints (pad-8)

    // preprocessing (4 dispatches)
    k_zeroinit<<<330, 256, 0, stream>>>(stats, counts, hb, ybuf);
    k_count<<<(N_EDGES + 255) / 256, 256, 0, stream>>>(ei, counts);
    k_scan<<<1, 1024, 0, stream>>>(counts, rowptr, cursor, dinv);
    k_prep<<<2043, 256, 0, stream>>>(x, hb, W[0], Wt0, ei, rowptr, counts,
                                     cursor, colidx, dinv);

    dim3 ggrid(8, N_PAD / 128);   // 632 blocks

    // layer 0: [agg(x') + aggw tail] -> G[256]; GEMM0 -> ybuf (leaky+stats0+prescale)
    k_agg<256, 2><<<2540, 256, 0, stream>>>(hb, rowptr, colidx, dinv, G, aggw,
            nullptr, nullptr, nullptr, nullptr, nullptr, nullptr);
    k_gemm<0, 0, 256><<<ggrid, 256, 0, stream>>>(G, Wt0, dinv, nullptr, bb[0], nullptr,
            nullptr, ybuf, nullptr, stats);

    // layers 1..3: [agg + fold_l tail] -> GEMM_l (leaky+stats_l+prescale)
    for (int l = 1; l < 4; l++) {
        k_agg<512, 1><<<2756, 256, 0, stream>>>(ybuf, rowptr, colidx, dinv, G, nullptr,
                W[l], gg[l - 1], beb[l - 1], stats + (l - 1) * 16384, Wts,
                cbuf + (l - 1) * 512);
        k_gemm<0, 1, 512><<<ggrid, 256, 0, stream>>>(G, Wts, dinv, aggw, bb[l], nullptr,
                cbuf + (l - 1) * 512, ybuf, nullptr, stats + l * 16384);
    }
    // layer 4: [agg + fold4 tail] -> GEMM4 (stats4, plain bf16 write)
    k_agg<512, 1><<<2756, 256, 0, stream>>>(ybuf, rowptr, colidx, dinv, G, nullptr,
            W[4], gg[3], beb[3], stats + 3 * 16384, Wts, cbuf + 3 * 512);
    k_gemm<1, 1, 512><<<ggrid, 256, 0, stream>>>(G, Wts, nullptr, aggw, bb[4], nullptr,
            cbuf + 3 * 512, ybuf, nullptr, stats + 4 * 16384);

    // final: fold5(Wf, stats4); GEMM5 -> out f32 (bias = cvec4 + bf)
    k_fold<<<dim3(16, 16), 256, 0, stream>>>(W[5], gg[4], beb[4],
            stats + 4 * 16384, Wts, cbuf + 4 * 512);
    k_gemm<2, 0, 512><<<ggrid, 256, 0, stream>>>(ybuf, Wts, nullptr, nullptr,
            cbuf + 4 * 512, bf, nullptr, nullptr, out, nullptr);
}

// Round 12
// 243.605 us; speedup vs baseline: 1.1513x; 1.0406x over previous
//
#include <hip/hip_runtime.h>
#include <hip/hip_bf16.h>
#include <type_traits>

#define N_NODES 10000
#define N_PAD   10112          // 79 * 128
#define N_EDGES 160000
#define D_H 512
#define BN_EPS 1e-5f
#define LEAKY_SLOPE 0.2f

typedef __attribute__((ext_vector_type(8))) __bf16 bf16x8;
typedef __attribute__((ext_vector_type(4))) __bf16 bf16x4;
typedef __attribute__((ext_vector_type(2))) __bf16 bf16x2;
typedef __attribute__((ext_vector_type(4))) float f32x4;

// ---- init: zero stats(5x16x1024)+cvec(5x512)=84480 f; counts; dummy rows ----

__global__ void k_zeroinit(float* fz, int* counts,
                           __hip_bfloat16* hb, __hip_bfloat16* ybuf) {
    int i = blockIdx.x * 256 + threadIdx.x;
    if (i < 84480) fz[i] = 0.f;
    if (i < N_NODES) counts[i] = 0;
    if (i < 128) ((unsigned int*)(hb + (size_t)N_NODES * 256))[i] = 0u;   // zero row (256 bf16)
    if (i < 256) ((unsigned int*)(ybuf + (size_t)N_NODES * D_H))[i] = 0u; // zero row (512 bf16)
}

__global__ void k_count(const int* __restrict__ ei, int* counts) {
    int e = blockIdx.x * blockDim.x + threadIdx.x;
    if (e < N_EDGES) atomicAdd(&counts[ei[N_EDGES + e]], 1);
}

// exclusive scan of counts padded to multiple of 8 -> rowptr/cursor;
// dinv[i] = rsqrtf(1 + count) (self-loop); dinv[dummy] = 0
__global__ __launch_bounds__(1024) void k_scan(const int* __restrict__ counts,
                                               int* rowptr, int* cursor, float* dinv) {
    __shared__ int sums[1024];
    int t = threadIdx.x;
    int vals[10];
    int base = t * 10;
    int s = 0;
    #pragma unroll
    for (int j = 0; j < 10; j++) {
        int idx = base + j;
        int v = 0;
        if (idx < N_NODES) {
            int c = counts[idx];
            v = (c + 7) & ~7;                            // pad to multiple of 8
            dinv[idx] = rsqrtf(1.0f + (float)c);         // deg = count + self-loop
        } else if (idx == N_NODES) {
            dinv[idx] = 0.f;                             // dummy node
        }
        vals[j] = v; s += v;
    }
    sums[t] = s;
    __syncthreads();
    for (int off = 1; off < 1024; off <<= 1) {
        int v = (t >= off) ? sums[t - off] : 0;
        __syncthreads();
        if (t >= off) sums[t] += v;
        __syncthreads();
    }
    int excl = (t == 0) ? 0 : sums[t - 1];
    #pragma unroll
    for (int j = 0; j < 10; j++) {
        int idx = base + j;
        if (idx < N_NODES) { rowptr[idx] = excl; cursor[idx] = excl; excl += vals[j]; }
    }
    if (t == 1023) rowptr[N_NODES] = sums[1023];
}

// ---- merged prep: xcvt (1250) | wt0 transpose (128) | fill (625) | pad (40) ----
// fill writes real CSR slots; pad writes [rowptr+count, rowptr_next) -- disjoint.

__global__ __launch_bounds__(256) void k_prep(const float* __restrict__ x,
        __hip_bfloat16* __restrict__ hb, const float* __restrict__ w,
        __hip_bfloat16* __restrict__ wt, const int* __restrict__ ei,
        const int* __restrict__ rowptr, const int* __restrict__ counts,
        int* cursor, int* colidx, const float* __restrict__ dinv) {
    int b = blockIdx.x;
    if (b < 1250) {
        int i = b * 256 + threadIdx.x;
        float di = dinv[i >> 5];                 // row = i*8/256
        size_t base = (size_t)i * 8;
        float4 a = *reinterpret_cast<const float4*>(x + base);
        float4 c = *reinterpret_cast<const float4*>(x + base + 4);
        bf16x8 o;
        o[0] = (__bf16)(a.x * di); o[1] = (__bf16)(a.y * di);
        o[2] = (__bf16)(a.z * di); o[3] = (__bf16)(a.w * di);
        o[4] = (__bf16)(c.x * di); o[5] = (__bf16)(c.y * di);
        o[6] = (__bf16)(c.z * di); o[7] = (__bf16)(c.w * di);
        *reinterpret_cast<bf16x8*>((unsigned short*)hb + base) = o;
    } else if (b < 1378) {
        int bb = b - 1250;                 // 128 blocks: 8 x 16 tiles of 32x32
        int r0 = (bb & 7) * 32;            // k dim (256)
        int c0 = (bb >> 3) * 32;           // out-col dim (512)
        __shared__ float t[32][33];
        int tx = threadIdx.x & 31, ty = threadIdx.x >> 5;
        for (int rr = ty; rr < 32; rr += 8)
            t[rr][tx] = w[(size_t)(r0 + rr) * 512 + c0 + tx];
        __syncthreads();
        for (int rr = ty; rr < 32; rr += 8)
            wt[(size_t)(c0 + rr) * 256 + r0 + tx] = __float2bfloat16(t[tx][rr]);
    } else if (b < 2003) {
        int e = (b - 1378) * 256 + threadIdx.x;
        if (e < N_EDGES) {
            int src = ei[e];
            int dst = ei[N_EDGES + e];
            int p = atomicAdd(&cursor[dst], 1);
            colidx[p] = src;
        }
    } else {
        int i = (b - 2003) * 256 + threadIdx.x;
        if (i < N_NODES) {
            int beg = rowptr[i] + counts[i], end = rowptr[i + 1];
            for (int e = beg; e < end; e++) colidx[e] = N_NODES;
        }
    }
}

// ---- BN fold body: Wts[col][k] = bf16(sc[k]*W[k][col]); cvec[col] += sh[k]*W[k][col] ----
// stats layout: 16 buckets x [sum(512) | sumsq(512)]

__device__ void fold_body(int r0, int c0, const float* __restrict__ W,
        const float* __restrict__ g, const float* __restrict__ beta,
        const float* __restrict__ stats, __hip_bfloat16* __restrict__ Wts,
        float* __restrict__ cvec) {
    __shared__ float t[32][33];
    __shared__ float scs[32], shs[32];
    __shared__ float cpart[8][32];
    int tx = threadIdx.x & 31, ty = threadIdx.x >> 5;
    if (threadIdx.x < 32) {
        int k = r0 + threadIdx.x;
        float ssum = 0.f, qsum = 0.f;
        #pragma unroll
        for (int b = 0; b < 16; b++) {
            ssum += stats[b * 1024 + k];
            qsum += stats[b * 1024 + 512 + k];
        }
        float mu = ssum * (1.f / N_NODES);
        float var = qsum * (1.f / N_NODES) - mu * mu;
        float sc = rsqrtf(var + BN_EPS) * g[k];
        scs[threadIdx.x] = sc;
        shs[threadIdx.x] = beta[k] - mu * sc;
    }
    for (int rr = ty; rr < 32; rr += 8)
        t[rr][tx] = W[(size_t)(r0 + rr) * 512 + c0 + tx];
    __syncthreads();
    for (int rr = ty; rr < 32; rr += 8)
        Wts[(size_t)(c0 + rr) * 512 + r0 + tx] = __float2bfloat16(t[tx][rr] * scs[tx]);
    float p = 0.f;
    #pragma unroll
    for (int k = 0; k < 4; ++k) p += shs[ty * 4 + k] * t[ty * 4 + k][tx];
    cpart[ty][tx] = p;
    __syncthreads();
    if (ty == 0) {
        float s = 0.f;
        #pragma unroll
        for (int k2 = 0; k2 < 8; ++k2) s += cpart[k2][tx];
        atomicAdd(&cvec[c0 + tx], s);
    }
}

__global__ __launch_bounds__(256) void k_fold(const float* __restrict__ W,
        const float* __restrict__ g, const float* __restrict__ beta,
        const float* __restrict__ stats, __hip_bfloat16* __restrict__ Wts,
        float* __restrict__ cvec) {
    fold_body(blockIdx.x * 32, blockIdx.y * 32, W, g, beta, stats, Wts, cvec);
}

// ---- gather-sum aggregation, COLUMN-HALF TEMPORAL SPLIT ----
// Item = (half, node): items 0..9999 process cols [0, C/2), items 10000..19999
// process cols [C/2, C). Blocks run roughly in dispatch order, so the active
// gather working set is halved (5 MB -> L2-friendly; 2.5 MB for layer 0).
// Column arithmetic identical to unsplit version -> bit-identical output.
// src rows PRE-SCALED by dinv[src]; CSR padded to 8, pads hit the zero row.
// dst[i] = dinv[i] * (src[i] + sum_e src[colidx[e]])
// TAIL: 0 none; 1 fold_body (front 256 blocks); 2 aggw compute (front 40 blocks)

template<int COLS, int TAIL>
__global__ __launch_bounds__(256) void k_agg(const __hip_bfloat16* __restrict__ src,
        const int* __restrict__ rowptr, const int* __restrict__ colidx,
        const float* __restrict__ dinv, __hip_bfloat16* __restrict__ dst,
        float* __restrict__ aggw,
        const float* __restrict__ W, const float* __restrict__ g,
        const float* __restrict__ beta, const float* __restrict__ stats,
        __hip_bfloat16* __restrict__ Wts, float* __restrict__ cvec) {
    int b = blockIdx.x;
    if (TAIL == 1) {
        if (b < 256) {                     // 256 blocks: 16 x 16 tiles of 32x32
            fold_body((b & 15) * 32, (b >> 4) * 32, W, g, beta, stats, Wts, cvec);
            return;
        }
        b -= 256;
    }
    if (TAIL == 2) {
        if (b < 40) {
            int i = b * 256 + threadIdx.x;
            if (i < N_NODES) {
                float di = dinv[i], s = di;
                int end = rowptr[i + 1];
                for (int e = rowptr[i]; e < end; e++) s += dinv[colidx[e]];  // pads add 0
                aggw[i] = di * s;
            }
            return;
        }
        b -= 40;
    }
    constexpr int HALF = COLS / 2;
    constexpr int VL = HALF / 64;          // 4 for COLS=512, 2 for COLS=256
    using vec_t = typename std::conditional<VL == 4, bf16x4, bf16x2>::type;
    int w = threadIdx.x >> 6, lane = threadIdx.x & 63;
    int item = b * 4 + w;                  // 0..19999 (5000 blocks)
    int half = (item >= N_NODES) ? 1 : 0;
    int node = item - half * N_NODES;
    int col0 = half * HALF + lane * VL;
    const __hip_bfloat16* base = src + col0;
    float di = dinv[node];
    vec_t v = *reinterpret_cast<const vec_t*>(base + (size_t)node * COLS);
    float s[VL];
    #pragma unroll
    for (int j = 0; j < VL; j++) s[j] = (float)v[j];
    int beg = rowptr[node], end = rowptr[node + 1];
    if (beg < end) {
        int4 iv0 = *reinterpret_cast<const int4*>(colidx + beg);
        int4 iv1 = *reinterpret_cast<const int4*>(colidx + beg + 4);
        for (int e = beg; e < end; e += 8) {
            int4 nv0 = iv0, nv1 = iv1;
            int en = e + 8;
            if (en < end) {                // prefetch next indices before consuming rows
                nv0 = *reinterpret_cast<const int4*>(colidx + en);
                nv1 = *reinterpret_cast<const int4*>(colidx + en + 4);
            }
            vec_t u0 = *reinterpret_cast<const vec_t*>(base + (size_t)iv0.x * COLS);
            vec_t u1 = *reinterpret_cast<const vec_t*>(base + (size_t)iv0.y * COLS);
            vec_t u2 = *reinterpret_cast<const vec_t*>(base + (size_t)iv0.z * COLS);
            vec_t u3 = *reinterpret_cast<const vec_t*>(base + (size_t)iv0.w * COLS);
            vec_t u4 = *reinterpret_cast<const vec_t*>(base + (size_t)iv1.x * COLS);
            vec_t u5 = *reinterpret_cast<const vec_t*>(base + (size_t)iv1.y * COLS);
            vec_t u6 = *reinterpret_cast<const vec_t*>(base + (size_t)iv1.z * COLS);
            vec_t u7 = *reinterpret_cast<const vec_t*>(base + (size_t)iv1.w * COLS);
            #pragma unroll
            for (int j = 0; j < VL; j++)
                s[j] += (((float)u0[j] + (float)u1[j]) + ((float)u2[j] + (float)u3[j]))
                      + (((float)u4[j] + (float)u5[j]) + ((float)u6[j] + (float)u7[j]));
            iv0 = nv0; iv1 = nv1;
        }
    }
    vec_t o;
    #pragma unroll
    for (int j = 0; j < VL; j++) o[j] = (__bf16)(di * s[j]);
    *reinterpret_cast<vec_t*>(dst + (size_t)node * COLS + col0) = o;
}

// ---- bf16 MFMA GEMM (128x64 tile, 2-phase dbuf, COUNTED vmcnt pipeline) ----
// MODE 0: val=acc+bias1(+aggw*cvec); leaky; stats; write bf16(val*dinv[row])   (layers 0-3)
// MODE 1: val=acc+bias1+aggw*cvec; stats; write bf16(val)                      (layer 4)
// MODE 2: write f32 acc+bias1+bias2                                            (final)

__device__ __forceinline__ void gload16(const void* g, void* l) {
    __builtin_amdgcn_global_load_lds(
        (const __attribute__((address_space(1))) void*)g,
        (__attribute__((address_space(3))) void*)l, 16, 0, 0);
}

template<int MODE, int HASR1, int K>
__global__ __launch_bounds__(256) void k_gemm(
        const __hip_bfloat16* __restrict__ A,    // [N_PAD x K] row-major
        const __hip_bfloat16* __restrict__ Bt,   // [512 x K] row-major
        const float* __restrict__ dinv, const float* __restrict__ aggw,
        const float* __restrict__ bias1, const float* __restrict__ bias2,
        const float* __restrict__ cvec,
        __hip_bfloat16* __restrict__ Cb, float* __restrict__ Cf,
        float* __restrict__ stats) {
    __shared__ alignas(16) __hip_bfloat16 As[2][128][32];
    __shared__ alignas(16) __hip_bfloat16 Bs[2][64][32];
    int lin = blockIdx.y * 8 + blockIdx.x;
    int nid = (lin & 7) * 79 + (lin >> 3);       // bijective XCD swizzle (632 = 8*79)
    int row0 = (nid >> 3) * 128;
    int col0 = (nid & 7) * 64;
    int tid = threadIdx.x;
    int lane = tid & 63;
    int w = tid >> 6;
    int wm = w >> 1, wn = w & 1;
    int sr = lane >> 2;
    int sk = (((lane & 3) ^ ((lane >> 3) & 3)) << 3);     // pre-swizzled global k offset
    int fl = lane & 15;
    int fso = (((lane >> 4) ^ ((lane >> 1) & 3)) << 3);   // swizzled frag slot offset

    const __hip_bfloat16* ga = A  + (size_t)(row0 + w * 16 + sr) * K + sk;
    const __hip_bfloat16* gb = Bt + (size_t)(col0 + w * 16 + sr) * K + sk;

    f32x4 acc[4][2] = {};
    constexpr int NSTEP = K / 32;

    // prologue: stage tile 0 (3 outstanding vmem ops per wave)
    gload16(ga, &As[0][w * 16][0]);
    gload16(ga + (size_t)64 * K, &As[0][(w + 4) * 16][0]);
    gload16(gb, &Bs[0][w * 16][0]);

    #pragma unroll
    for (int t = 0; t < NSTEP; ++t) {
        int cur = t & 1;
        if (t + 1 < NSTEP) {
            // stage next tile; wait only CURRENT tile's 3 loads (next's 3 stay in flight)
            int k0 = (t + 1) * 32;
            gload16(ga + k0, &As[cur ^ 1][w * 16][0]);
            gload16(ga + (size_t)64 * K + k0, &As[cur ^ 1][(w + 4) * 16][0]);
            gload16(gb + k0, &Bs[cur ^ 1][w * 16][0]);
            asm volatile("s_waitcnt vmcnt(3)\n\ts_barrier" ::: "memory");
        } else {
            asm volatile("s_waitcnt vmcnt(0)\n\ts_barrier" ::: "memory");
        }
        bf16x8 af[4], bfr[2];
        #pragma unroll
        for (int i = 0; i < 4; ++i)
            af[i]  = *reinterpret_cast<const bf16x8*>(&As[cur][wm * 64 + i * 16 + fl][fso]);
        #pragma unroll
        for (int j = 0; j < 2; ++j)
            bfr[j] = *reinterpret_cast<const bf16x8*>(&Bs[cur][wn * 32 + j * 16 + fl][fso]);
        #pragma unroll
        for (int i = 0; i < 4; ++i)
            #pragma unroll
            for (int j = 0; j < 2; ++j)
                acc[i][j] = __builtin_amdgcn_mfma_f32_16x16x32_bf16(af[i], bfr[j], acc[i][j], 0, 0, 0);
        // all this wave's ds_reads complete before barrier -> next iter's stage
        // can't overwrite a buffer another wave is still reading
        asm volatile("s_waitcnt lgkmcnt(0)\n\ts_barrier" ::: "memory");
    }

    int rg = (lane >> 4) * 4;             // C/D: col=lane&15, row=(lane>>4)*4+reg
    float sp0 = 0.f, sp1 = 0.f, qp0 = 0.f, qp1 = 0.f;
    #pragma unroll
    for (int i = 0; i < 4; ++i) {
        #pragma unroll
        for (int r = 0; r < 4; ++r) {
            int row = row0 + wm * 64 + i * 16 + rg + r;
            if (row < N_NODES) {
                float r1 = HASR1 ? aggw[row] : 0.f;
                float dsc = (MODE == 0) ? dinv[row] : 1.f;
                #pragma unroll
                for (int j = 0; j < 2; ++j) {
                    int col = col0 + wn * 32 + j * 16 + fl;
                    float val = acc[i][j][r] + bias1[col];
                    if (HASR1) val += r1 * cvec[col];
                    if (MODE == 0) val = (val >= 0.f) ? val : LEAKY_SLOPE * val;
                    if (MODE <= 1) {
                        if (j == 0) { sp0 += val; qp0 += val * val; }
                        else        { sp1 += val; qp1 += val * val; }
                    }
                    if (MODE == 2) Cf[(size_t)row * D_H + col] = val + bias2[col];
                    else           Cb[(size_t)row * D_H + col] = __float2bfloat16(val * dsc);
                }
            }
        }
    }
    if (MODE <= 1) {                      // fused BN-stats reduce (reuse LDS)
        float* red = reinterpret_cast<float*>(&As[0][0][0]);   // [2][512]
        int cl = wn * 32 + fl;            // col_local for j=0; +16 for j=1
        int contrib = wm * 4 + (lane >> 4);
        red[cl * 8 + contrib]          = sp0;
        red[(cl + 16) * 8 + contrib]   = sp1;
        red[512 + cl * 8 + contrib]        = qp0;
        red[512 + (cl + 16) * 8 + contrib] = qp1;
        __syncthreads();
        if (tid < 128) {
            int c = tid >> 1, isq = tid & 1;
            float ssum = 0.f;
            #pragma unroll
            for (int k = 0; k < 8; k++) ssum += red[isq * 512 + c * 8 + k];
            atomicAdd(&stats[(nid & 15) * 1024 + isq * 512 + col0 + c], ssum);
        }
    }
}

// ---------------- launch ----------------

extern "C" void kernel_launch(void* const* d_in, const int* in_sizes, int n_in,
                              void* d_out, int out_size, void* d_ws, size_t ws_size,
                              hipStream_t stream) {
    (void)in_sizes; (void)n_in; (void)out_size; (void)ws_size;
    const float* x  = (const float*)d_in[0];
    const int*   ei = (const int*)d_in[1];
    const float *W[6], *bb[5], *gg[5], *beb[5];
    for (int i = 0; i < 5; i++) {
        W[i]   = (const float*)d_in[2 + 4 * i];
        bb[i]  = (const float*)d_in[3 + 4 * i];
        gg[i]  = (const float*)d_in[4 + 4 * i];
        beb[i] = (const float*)d_in[5 + 4 * i];
    }
    W[5] = (const float*)d_in[22];
    const float* bf = (const float*)d_in[23];
    float* out = (float*)d_out;

    // workspace layout (all chunks 16B-aligned)
    char* p = (char*)d_ws;
    __hip_bfloat16* hb   = (__hip_bfloat16*)p;  p += (size_t)N_PAD * 256 * 2;   // x*dinv
    __hip_bfloat16* G    = (__hip_bfloat16*)p;  p += (size_t)N_PAD * D_H * 2;   // agg output
    __hip_bfloat16* ybuf = (__hip_bfloat16*)p;  p += (size_t)N_PAD * D_H * 2;   // gemm output
    __hip_bfloat16* Wt0  = (__hip_bfloat16*)p;  p += (size_t)D_H * 256 * 2;
    __hip_bfloat16* Wts  = (__hip_bfloat16*)p;  p += (size_t)D_H * 512 * 2;
    float* stats  = (float*)p;  p += 5 * 16384 * 4;  // [5][16 buckets][1024]
    float* cbuf   = (float*)p;  p += 5 * 512 * 4;    // contiguous with stats for zeroing
    float* dinv   = (float*)p;  p += 10008 * 4;      // [10000]=dummy 0
    float* aggw   = (float*)p;  p += N_NODES * 4;
    int* counts   = (int*)p;    p += N_NODES * 4;
    int* rowptr   = (int*)p;    p += 10004 * 4;
    int* cursor   = (int*)p;    p += N_NODES * 4;
    int* colidx   = (int*)p;                         // <= 230000 ints (pad-8)

    // preprocessing (4 dispatches)
    k_zeroinit<<<330, 256, 0, stream>>>(stats, counts, hb, ybuf);
    k_count<<<(N_EDGES + 255) / 256, 256, 0, stream>>>(ei, counts);
    k_scan<<<1, 1024, 0, stream>>>(counts, rowptr, cursor, dinv);
    k_prep<<<2043, 256, 0, stream>>>(x, hb, W[0], Wt0, ei, rowptr, counts,
                                     cursor, colidx, dinv);

    dim3 ggrid(8, N_PAD / 128);   // 632 blocks

    // layer 0: [aggw tail + agg(x') split] -> G[256]; GEMM0 -> ybuf
    k_agg<256, 2><<<5040, 256, 0, stream>>>(hb, rowptr, colidx, dinv, G, aggw,
            nullptr, nullptr, nullptr, nullptr, nullptr, nullptr);
    k_gemm<0, 0, 256><<<ggrid, 256, 0, stream>>>(G, Wt0, dinv, nullptr, bb[0], nullptr,
            nullptr, ybuf, nullptr, stats);

    // layers 1..3: [fold_l front + agg split] -> GEMM_l (leaky+stats_l+prescale)
    for (int l = 1; l < 4; l++) {
        k_agg<512, 1><<<5256, 256, 0, stream>>>(ybuf, rowptr, colidx, dinv, G, nullptr,
                W[l], gg[l - 1], beb[l - 1], stats + (l - 1) * 16384, Wts,
                cbuf + (l - 1) * 512);
        k_gemm<0, 1, 512><<<ggrid, 256, 0, stream>>>(G, Wts, dinv, aggw, bb[l], nullptr,
                cbuf + (l - 1) * 512, ybuf, nullptr, stats + l * 16384);
    }
    // layer 4: [fold4 front + agg split] -> GEMM4 (stats4, plain bf16 write)
    k_agg<512, 1><<<5256, 256, 0, stream>>>(ybuf, rowptr, colidx, dinv, G, nullptr,
            W[4], gg[3], beb[3], stats + 3 * 16384, Wts, cbuf + 3 * 512);
    k_gemm<1, 1, 512><<<ggrid, 256, 0, stream>>>(G, Wts, nullptr, aggw, bb[4], nullptr,
            cbuf + 3 * 512, ybuf, nullptr, stats + 4 * 16384);

    // final: fold5(Wf, stats4); GEMM5 -> out f32 (bias = cvec4 + bf)
    k_fold<<<dim3(16, 16), 256, 0, stream>>>(W[5], gg[4], beb[4],
            stats + 4 * 16384, Wts, cbuf + 4 * 512);
    k_gemm<2, 0, 512><<<ggrid, 256, 0, stream>>>(ybuf, Wts, nullptr, nullptr,
            cbuf + 4 * 512, bf, nullptr, nullptr, out, nullptr);
}